// Round 1
// baseline (73.384 us; speedup 1.0000x reference)
//
#include <hip/hip_runtime.h>

// Geometric product in Cl(3,0), blades short-lex ordered:
// idx: 0=1, 1=e1, 2=e2, 3=e3, 4=e12, 5=e13, 6=e23, 7=e123
// Hardcoded 64-term signed product table (METRIC=[1,1,1] fixed in setup_inputs).
// Memory-bound streaming kernel: 1 thread = 1 multivector pair (32B each).

__global__ __launch_bounds__(256) void clifford_gp_kernel(
    const float4* __restrict__ a4, const float4* __restrict__ b4,
    float4* __restrict__ o4, int n_mv)
{
    int t = blockIdx.x * blockDim.x + threadIdx.x;
    if (t >= n_mv) return;

    float4 alo = a4[2 * t], ahi = a4[2 * t + 1];
    float4 blo = b4[2 * t], bhi = b4[2 * t + 1];

    float a0 = alo.x, a1 = alo.y, a2 = alo.z, a3 = alo.w;
    float A4 = ahi.x, a5 = ahi.y, a6 = ahi.z, a7 = ahi.w;
    float b0 = blo.x, b1 = blo.y, b2 = blo.z, b3 = blo.w;
    float B4 = bhi.x, b5 = bhi.y, b6 = bhi.z, b7 = bhi.w;

    float4 olo, ohi;
    // scalar
    olo.x = a0*b0 + a1*b1 + a2*b2 + a3*b3 - A4*B4 - a5*b5 - a6*b6 - a7*b7;
    // e1
    olo.y = a0*b1 + a1*b0 - a2*B4 + A4*b2 - a3*b5 + a5*b3 - a6*b7 - a7*b6;
    // e2
    olo.z = a0*b2 + a2*b0 + a1*B4 - A4*b1 - a3*b6 + a6*b3 + a5*b7 + a7*b5;
    // e3
    olo.w = a0*b3 + a3*b0 + a1*b5 - a5*b1 + a2*b6 - a6*b2 - A4*b7 - a7*B4;
    // e12
    ohi.x = a0*B4 + A4*b0 + a1*b2 - a2*b1 + a3*b7 + a7*b3 - a5*b6 + a6*b5;
    // e13
    ohi.y = a0*b5 + a5*b0 + a1*b3 - a3*b1 - a2*b7 - a7*b2 + A4*b6 - a6*B4;
    // e23
    ohi.z = a0*b6 + a6*b0 + a2*b3 - a3*b2 + a1*b7 + a7*b1 - A4*b5 + a5*B4;
    // e123
    ohi.w = a0*b7 + a7*b0 + a1*b6 + a6*b1 - a2*b5 - a5*b2 + a3*B4 + A4*b3;

    o4[2 * t]     = olo;
    o4[2 * t + 1] = ohi;
}

extern "C" void kernel_launch(void* const* d_in, const int* in_sizes, int n_in,
                              void* d_out, int out_size, void* d_ws, size_t ws_size,
                              hipStream_t stream) {
    const float4* a = (const float4*)d_in[0];
    const float4* b = (const float4*)d_in[1];
    float4* out = (float4*)d_out;
    int n_mv = in_sizes[0] / 8;  // 65536*64 = 4,194,304 multivectors
    int block = 256;
    int grid = (n_mv + block - 1) / block;
    clifford_gp_kernel<<<grid, block, 0, stream>>>(a, b, out, n_mv);
}